// Round 15
// baseline (76.143 us; speedup 1.0000x reference)
//
#include <hip/hip_runtime.h>
#include <hip/hip_bf16.h>

#define VOCAB 50257
#define NTAGS 50
#define EMB   128
#define NTOK  262144
#define KD    640     // (2*CTX+1) * EMB
#define WPAD  64      // (fallback) tags padded to 4 MFMA tiles

#define TAGP  64      // per-position padded tag slots (slice = 128 B, line-aligned)
#define NZ    320     // 5 positions * TAGP
#define ZROWS 50304   // 393*128 rows (rows >= VOCAB are zero sentinels)

#define TOK   24      // tokens per tile
#define RWS   28      // staged rows per tile (24 + 4 halo)
#define CHR   40      // 16B chunks per ZT row (640 B)
#define NCHUNK (RWS*CHR)          // 1120
#define NITER  ((NCHUNK+63)/64)   // 18
#define TILEB  17920              // bytes per staged tile (1120*16)

typedef __attribute__((ext_vector_type(4))) float f32x4;
typedef __attribute__((ext_vector_type(8))) short bf16x8;

__device__ __forceinline__ ushort f2bf(float f) {
    union { float f; unsigned u; } v; v.f = f;
    unsigned u = v.u;
    return (ushort)((u + 0x7fffu + ((u >> 16) & 1u)) >> 16);  // RNE
}

__device__ __forceinline__ void gload_lds16(const void* g, void* l) {
    __builtin_amdgcn_global_load_lds(
        (const __attribute__((address_space(1))) unsigned*)g,
        (__attribute__((address_space(3))) unsigned*)l, 16, 0, 0);
}

// ============================ primary path ============================

// Wt bf16, PRE-SWIZZLED: chunk j of row n (n = p*64+tag) stored at byte
// n*256 + (j^(n&7))*16.  Rows with tag>=50 are zero.  5120 threads.
__global__ void conv_k(const float* __restrict__ W, ushort* __restrict__ Wt) {
    int g = blockIdx.x * blockDim.x + threadIdx.x;   // flat chunk 0..5119
    if (g >= NZ * 16) return;
    int n = g >> 4, j = g & 15;
    int tg = n & 63, p = n >> 6;
    bf16x8 val = (bf16x8){0,0,0,0,0,0,0,0};
    if (tg < NTAGS) {
        const float* wp = W + tg * KD + p * EMB + j * 8;
        f32x4 lo = *(const f32x4*)wp;
        f32x4 hi = *(const f32x4*)(wp + 4);
        val[0]=(short)f2bf(lo[0]); val[1]=(short)f2bf(lo[1]);
        val[2]=(short)f2bf(lo[2]); val[3]=(short)f2bf(lo[3]);
        val[4]=(short)f2bf(hi[0]); val[5]=(short)f2bf(hi[1]);
        val[6]=(short)f2bf(hi[2]); val[7]=(short)f2bf(hi[3]);
    }
    *(bf16x8*)((char*)Wt + n * 256 + ((j ^ (n & 7)) << 4)) = val;
}

// ZT[v][p*64+tag] = emb[v] . W[tag][p*128 : p*128+128]   (bf16 out)
__global__ __launch_bounds__(256)
void zt_k(const float* __restrict__ emb, const ushort* __restrict__ Wt,
          ushort* __restrict__ ZT) {
    __shared__ __align__(16) char wlds[NZ * EMB * 2];   // 80 KB, chunk-swizzled

    const int tid  = threadIdx.x;
    const int lane = tid & 63;
    const int c = lane & 15, q = lane >> 4;
    const int vb = blockIdx.x * 128;
    const int wave = tid >> 6;

    // ---- issue E loads first (independent, fly under the W DMA) ----
    f32x4 Elo[2][4], Ehi[2][4];
    #pragma unroll
    for (int nv = 0; nv < 2; ++nv) {
        int row = vb + wave * 32 + nv * 16 + c;
        bool ok = row < VOCAB;
        const float* rp = emb + (size_t)(ok ? row : 0) * EMB;
        #pragma unroll
        for (int kk = 0; kk < 4; ++kk) {
            Elo[nv][kk] = ok ? *(const f32x4*)(rp + kk * 32 + q * 8)
                             : (f32x4){0,0,0,0};
            Ehi[nv][kk] = ok ? *(const f32x4*)(rp + kk * 32 + q * 8 + 4)
                             : (f32x4){0,0,0,0};
        }
    }

    // ---- stage W: 5120 chunks, linear async DMA (swizzle baked into Wt) ----
    #pragma unroll
    for (int it = 0; it < 20; ++it) {
        int g = it * 256 + tid;
        gload_lds16((const char*)Wt + g * 16, wlds + it * 4096 + wave * 1024);
    }

    // ---- convert E to bf16 (VALU; overlaps DMA drain) ----
    bf16x8 E[2][4];
    #pragma unroll
    for (int nv = 0; nv < 2; ++nv)
        #pragma unroll
        for (int kk = 0; kk < 4; ++kk) {
            bf16x8 a;
            a[0]=(short)f2bf(Elo[nv][kk][0]); a[1]=(short)f2bf(Elo[nv][kk][1]);
            a[2]=(short)f2bf(Elo[nv][kk][2]); a[3]=(short)f2bf(Elo[nv][kk][3]);
            a[4]=(short)f2bf(Ehi[nv][kk][0]); a[5]=(short)f2bf(Ehi[nv][kk][1]);
            a[6]=(short)f2bf(Ehi[nv][kk][2]); a[7]=(short)f2bf(Ehi[nv][kk][3]);
            E[nv][kk] = a;
        }
    __syncthreads();

    #pragma unroll
    for (int ng = 0; ng < 5; ++ng) {        // ng == position p
        bf16x8 Wf[4][4];
        #pragma unroll
        for (int mtag = 0; mtag < 4; ++mtag) {
            #pragma unroll
            for (int kk = 0; kk < 4; ++kk) {
                int r  = ng * 64 + mtag * 16 + c;         // Wt row
                int ph = (kk * 4 + q) ^ (c & 7);          // phys chunk (r&7 == c&7)
                Wf[mtag][kk] = *(const bf16x8*)(wlds + r * 256 + ph * 16);
            }
        }
        f32x4 acc[4][2];
        #pragma unroll
        for (int mtag = 0; mtag < 4; ++mtag)
            #pragma unroll
            for (int nv = 0; nv < 2; ++nv)
                acc[mtag][nv] = (f32x4){0.f,0.f,0.f,0.f};
        #pragma unroll
        for (int kk = 0; kk < 4; ++kk)
            #pragma unroll
            for (int mtag = 0; mtag < 4; ++mtag)
                #pragma unroll
                for (int nv = 0; nv < 2; ++nv)
                    acc[mtag][nv] = __builtin_amdgcn_mfma_f32_16x16x32_bf16(
                        Wf[mtag][kk], E[nv][kk], acc[mtag][nv], 0, 0, 0);
        #pragma unroll
        for (int nv = 0; nv < 2; ++nv) {
            const size_t row = (size_t)(vb + wave * 32 + nv * 16 + c);
            #pragma unroll
            for (int mtag = 0; mtag < 4; ++mtag) {
                ushort4 o = { f2bf(acc[mtag][nv][0]), f2bf(acc[mtag][nv][1]),
                              f2bf(acc[mtag][nv][2]), f2bf(acc[mtag][nv][3]) };
                *(ushort4*)(ZT + row * NZ + ng * 64 + mtag * 16 + q * 4) = o;
            }
        }
    }
}

// per 48-token block: TWO 24-token tiles double-buffered with counted vmcnt —
// issue A-DMAs + B-DMAs, wait vmcnt(18), compute A (hides B's drain),
// wait vmcnt(0), compute B; results transposed in LDS, one NT store pass.
__global__ __launch_bounds__(64, 1)
void tag_k(const int* __restrict__ tokens, const ushort* __restrict__ ZT,
           const float* __restrict__ bias, float* __restrict__ out) {
    __shared__ __align__(16) char smem[2 * TILEB + 224];   // tiles A,B + ids
    int* ids = (int*)(smem + 2 * TILEB);

    const int l  = threadIdx.x;
    const long bb = (long)blockIdx.x * 48;

    // ---- ids[0..51]: token bb-2+i (clamped to zero-row sentinel) ----
    if (l < 52) {
        long t = bb - 2 + l;
        ids[l] = (t >= 0 && t < NTOK) ? tokens[t] : VOCAB;
    }
    __syncthreads();

    // ---- batched id reads for both tiles ----
    int tkA[NITER], tkB[NITER];
    #pragma unroll
    for (int w = 0; w < NITER; ++w) {
        int g = w * 64 + l;
        int r = (g < NCHUNK) ? (g / CHR) : 0;
        tkA[w] = ids[r];
        tkB[w] = ids[24 + r];
    }

    // ---- issue tile A DMAs, then tile B DMAs (36 wave-instrs in flight) ----
    #pragma unroll
    for (int w = 0; w < NITER; ++w) {
        int g = w * 64 + l;
        if (g < NCHUNK) {
            int r  = g / CHR;
            int ch = g - r * CHR;
            int i  = ch & 7, p = ch >> 3;
            gload_lds16((const char*)ZT + (size_t)tkA[w] * 640
                        + p * 128 + ((i ^ (r & 7)) << 4), smem + w * 1024);
        }
    }
    #pragma unroll
    for (int w = 0; w < NITER; ++w) {
        int g = w * 64 + l;
        if (g < NCHUNK) {
            int r  = g / CHR;
            int ch = g - r * CHR;
            int i  = ch & 7, p = ch >> 3;
            gload_lds16((const char*)ZT + (size_t)tkB[w] * 640
                        + p * 128 + ((i ^ (r & 7)) << 4), smem + TILEB + w * 1024);
        }
    }

    float b48 = bias[48], b49 = bias[49];
    float4 bv[12];
    #pragma unroll
    for (int g = 0; g < 12; ++g) bv[g] = *(const float4*)(bias + g * 4);

    // ================= tile A: wait only its 18 DMAs =================
    asm volatile("s_waitcnt vmcnt(18)" ::: "memory");
    __builtin_amdgcn_sched_barrier(0);
    {
        float acc[56];
        #pragma unroll
        for (int g = 0; g < 12; ++g) {
            acc[g*4+0] = bv[g].x; acc[g*4+1] = bv[g].y;
            acc[g*4+2] = bv[g].z; acc[g*4+3] = bv[g].w;
        }
        acc[48] = b48; acc[49] = b49;
        #pragma unroll
        for (int j = 50; j < 56; ++j) acc[j] = 0.f;

        const int le = (l < TOK) ? l : (TOK - 1);
        #pragma unroll
        for (int p = 0; p < 5; ++p) {
            const int rp = le + p;
            const char* rb = smem + rp * 640;
            const int rx = (rp & 7) << 4;
            #pragma unroll
            for (int j = 0; j < 7; ++j) {
                bf16x8 v = *(const bf16x8*)(rb + p * 128 + ((j << 4) ^ rx));
                #pragma unroll
                for (int e = 0; e < 8; ++e) {
                    unsigned u = (unsigned)(ushort)v[e] << 16;
                    acc[j*8+e] += __uint_as_float(u);
                }
            }
        }
        float m = acc[0];
        #pragma unroll
        for (int j = 1; j < NTAGS; ++j) m = fmaxf(m, acc[j]);
        float s = 0.f;
        #pragma unroll
        for (int j = 0; j < NTAGS; ++j) s += __expf(acc[j] - m);
        const float L = m + __logf(s);
        if (l < TOK) {   // write results into transpose area (tileA region, rows already consumed)
            #pragma unroll
            for (int k = 0; k < 25; ++k) {
                float2 st = { acc[2*k] - L, acc[2*k+1] - L };
                *(float2*)(smem + (size_t)l * 200 + k * 8) = st;
            }
        }
    }

    // ================= tile B: drain the rest =================
    asm volatile("s_waitcnt vmcnt(0)" ::: "memory");
    __builtin_amdgcn_sched_barrier(0);
    {
        float acc[56];
        #pragma unroll
        for (int g = 0; g < 12; ++g) {
            acc[g*4+0] = bv[g].x; acc[g*4+1] = bv[g].y;
            acc[g*4+2] = bv[g].z; acc[g*4+3] = bv[g].w;
        }
        acc[48] = b48; acc[49] = b49;
        #pragma unroll
        for (int j = 50; j < 56; ++j) acc[j] = 0.f;

        const int le = (l < TOK) ? l : (TOK - 1);
        #pragma unroll
        for (int p = 0; p < 5; ++p) {
            const int rp = le + p;
            const char* rb = smem + TILEB + rp * 640;
            const int rx = (rp & 7) << 4;
            #pragma unroll
            for (int j = 0; j < 7; ++j) {
                bf16x8 v = *(const bf16x8*)(rb + p * 128 + ((j << 4) ^ rx));
                #pragma unroll
                for (int e = 0; e < 8; ++e) {
                    unsigned u = (unsigned)(ushort)v[e] << 16;
                    acc[j*8+e] += __uint_as_float(u);
                }
            }
        }
        float m = acc[0];
        #pragma unroll
        for (int j = 1; j < NTAGS; ++j) m = fmaxf(m, acc[j]);
        float s = 0.f;
        #pragma unroll
        for (int j = 0; j < NTAGS; ++j) s += __expf(acc[j] - m);
        const float L = m + __logf(s);
        if (l < TOK) {
            #pragma unroll
            for (int k = 0; k < 25; ++k) {
                float2 st = { acc[2*k] - L, acc[2*k+1] - L };
                *(float2*)(smem + (size_t)(24 + l) * 200 + k * 8) = st;
            }
        }
    }

    // ---- one NT store pass: 48 tokens x 200 B from the transpose area ----
    asm volatile("s_waitcnt lgkmcnt(0)" ::: "memory");
    __builtin_amdgcn_sched_barrier(0);
    const long nvalid = (NTOK - bb < 48) ? (NTOK - bb) : 48;
    const int nbytes = (int)(nvalid * 200);
    char* ob = (char*)out + (size_t)bb * 200;
    #pragma unroll
    for (int w = 0; w < 10; ++w) {
        int off = w * 1024 + l * 16;
        if (off < nbytes) {
            f32x4 d = *(const f32x4*)(smem + off);
            __builtin_nontemporal_store(d, (f32x4*)(ob + off));
        }
    }
}

// ============================ fallback path (R4, needs only ~13 MB ws) ============================
__global__ void fb_conv_k(const float* __restrict__ emb, const float* __restrict__ W,
                          ushort* __restrict__ embb, ushort* __restrict__ wb) {
    const int etotal = (VOCAB + 1) * EMB;
    int idx = (blockIdx.x * blockDim.x + threadIdx.x) * 4;
    if (idx < etotal) {
        float4 v = {0.f, 0.f, 0.f, 0.f};
        if (idx < VOCAB * EMB) v = *(const float4*)(emb + idx);
        ushort4 o = { f2bf(v.x), f2bf(v.y), f2bf(v.z), f2bf(v.w) };
        *(ushort4*)(embb + idx) = o;
    } else {
        int wi = idx - etotal;
        if (wi < WPAD * KD) {
            #pragma unroll
            for (int k = 0; k < 4; ++k) {
                int j = wi + k;
                int tag = j / KD;
                wb[j] = f2bf(tag < NTAGS ? W[j] : 0.f);
            }
        }
    }
}

__global__ __launch_bounds__(64, 2)
void fb_tag_k(const int* __restrict__ tokens, const ushort* __restrict__ embb,
              const ushort* __restrict__ Wb, const float* __restrict__ bias,
              float* __restrict__ out) {
    __shared__ ushort smem[68 * EMB];
    const int lane = threadIdx.x & 63;
    const int c = lane & 15;
    const int q = lane >> 4;
    const int bb = blockIdx.x * 64;
    const int rsub = lane >> 4;

    int tokid[17];
    #pragma unroll
    for (int g = 0; g < 17; ++g) {
        int t = bb - 2 + g * 4 + rsub;
        tokid[g] = (t >= 0 && t < NTOK) ? tokens[t] : VOCAB;
    }
    const ushort* bp[4];
    #pragma unroll
    for (int nt = 0; nt < 4; ++nt)
        bp[nt] = Wb + (nt * 16 + c) * KD + q * 8;
    bf16x8 Bb[4][4];
    #pragma unroll
    for (int s = 0; s < 4; ++s)
        #pragma unroll
        for (int nt = 0; nt < 4; ++nt)
            Bb[s][nt] = *(const bf16x8*)(bp[nt] + (s >> 2) * 128 + (s & 3) * 32);
    float bv[4];
    #pragma unroll
    for (int nt = 0; nt < 4; ++nt) {
        int tag = nt * 16 + c;
        bv[nt] = bias[tag < NTAGS ? tag : NTAGS - 1];
    }
    {
        const int pc = lane & 15;
        #pragma unroll
        for (int g = 0; g < 17; ++g) {
            int i = g * 4 + rsub;
            int sc = pc ^ (i & 7);
            gload_lds16(embb + (size_t)tokid[g] * EMB + sc * 8, (char*)smem + g * 1024);
        }
    }
    __syncthreads();

    f32x4 acc[4][4];
    #pragma unroll
    for (int mt = 0; mt < 4; ++mt)
        #pragma unroll
        for (int nt = 0; nt < 4; ++nt)
            acc[mt][nt] = (f32x4){0.f, 0.f, 0.f, 0.f};
    bf16x8 Ab[2][4];
    #pragma unroll
    for (int s = 0; s < 2; ++s) {
        int p = s >> 2, kk = s & 3;
        int ch = (4 * kk + q) ^ ((c + p) & 7);
        const char* ab = (const char*)smem + (c + p) * 256 + ch * 16;
        #pragma unroll
        for (int mt = 0; mt < 4; ++mt)
            Ab[s][mt] = *(const bf16x8*)(ab + mt * 4096);
    }
    #pragma unroll
    for (int s = 0; s < 20; ++s) {
        __builtin_amdgcn_s_setprio(1);
        #pragma unroll
        for (int mt = 0; mt < 4; ++mt)
            #pragma unroll
            for (int nt = 0; nt < 4; ++nt)
                acc[mt][nt] = __builtin_amdgcn_mfma_f32_16x16x32_bf16(
                    Ab[s & 1][mt], Bb[s & 3][nt], acc[mt][nt], 0, 0, 0);
        __builtin_amdgcn_s_setprio(0);
        if (s + 4 < 20) {
            const int tt = s + 4, p = tt >> 2, kk = tt & 3;
            #pragma unroll
            for (int nt = 0; nt < 4; ++nt)
                Bb[s & 3][nt] = *(const bf16x8*)(bp[nt] + p * 128 + kk * 32);
        }
        if (s + 2 < 20) {
            const int tt = s + 2, p = tt >> 2, kk = tt & 3;
            int ch = (4 * kk + q) ^ ((c + p) & 7);
            const char* ab = (const char*)smem + (c + p) * 256 + ch * 16;
            #pragma unroll
            for (int mt = 0; mt < 4; ++mt)
                Ab[s & 1][mt] = *(const bf16x8*)(ab + mt * 4096);
        }
    }
    #pragma unroll
    for (int mt = 0; mt < 4; ++mt) {
        #pragma unroll
        for (int j = 0; j < 4; ++j) {
            const int row = bb + mt * 16 + q * 4 + j;
            float x[4];
            float m = -1e30f;
            #pragma unroll
            for (int nt = 0; nt < 4; ++nt) {
                float xv = acc[mt][nt][j] + bv[nt];
                x[nt] = xv;
                if (nt * 16 + c < NTAGS) m = fmaxf(m, xv);
            }
            #pragma unroll
            for (int mask = 8; mask >= 1; mask >>= 1)
                m = fmaxf(m, __shfl_xor(m, mask));
            float s = 0.f;
            #pragma unroll
            for (int nt = 0; nt < 4; ++nt)
                if (nt * 16 + c < NTAGS) s += __expf(x[nt] - m);
            #pragma unroll
            for (int mask = 8; mask >= 1; mask >>= 1)
                s += __shfl_xor(s, mask);
            const float L = m + __logf(s);
            #pragma unroll
            for (int nt = 0; nt < 4; ++nt) {
                int tag = nt * 16 + c;
                if (tag < NTAGS) out[row * NTAGS + tag] = x[nt] - L;
            }
        }
    }
}

extern "C" void kernel_launch(void* const* d_in, const int* in_sizes, int n_in,
                              void* d_out, int out_size, void* d_ws, size_t ws_size,
                              hipStream_t stream) {
    const int*   tokens = (const int*)d_in[0];
    const float* emb    = (const float*)d_in[1];
    const float* W      = (const float*)d_in[2];
    const float* b      = (const float*)d_in[3];
    float* out = (float*)d_out;

    const size_t NEED = 81920ull + (size_t)ZROWS * NZ * 2ull;   // ~32.3 MB
    if (ws_size >= NEED) {
        ushort* Wt = (ushort*)d_ws;                             // 80 KB pre-swizzled
        ushort* ZT = (ushort*)((char*)d_ws + 81920);            // ZROWS x 320 bf16
        conv_k<<<20, 256, 0, stream>>>(W, Wt);
        zt_k<<<ZROWS / 128, 256, 0, stream>>>(emb, Wt, ZT);
        const int nblk = (int)((NTOK + 47) / 48);               // 5462
        tag_k<<<nblk, 64, 0, stream>>>(tokens, ZT, b, out);
    } else {
        ushort* embb = (ushort*)d_ws;
        ushort* Wb   = embb + (size_t)(VOCAB + 1) * EMB;
        const int etotal = (VOCAB + 1) * EMB;
        const int total4 = (etotal + WPAD * KD) / 4;
        fb_conv_k<<<(total4 + 255) / 256, 256, 0, stream>>>(emb, W, embb, Wb);
        fb_tag_k<<<NTOK / 64, 64, 0, stream>>>(tokens, embb, Wb, b, out);
    }
}

// Round 16
// 66.615 us; speedup vs baseline: 1.1430x; 1.1430x over previous
//
#include <hip/hip_runtime.h>
#include <hip/hip_bf16.h>

#define VOCAB 50257
#define NTAGS 50
#define EMB   128
#define NTOK  262144
#define KD    640     // (2*CTX+1) * EMB
#define WPAD  64      // (fallback) tags padded to 4 MFMA tiles

#define TAGP  64      // per-position padded tag slots (slice = 128 B, line-aligned)
#define NZ    320     // 5 positions * TAGP
#define ZROWS 50304   // 393*128 rows (rows >= VOCAB are zero sentinels)

#define TOK   24      // tokens per tag_k block (LDS ~18 KB -> 8 blocks/CU)
#define RWS   28      // staged rows (24 + 4 halo)
#define CHR   40      // 16B chunks per ZT row (640 B)
#define NCHUNK (RWS*CHR)          // 1120
#define NITER  ((NCHUNK+63)/64)   // 18

typedef __attribute__((ext_vector_type(4))) float f32x4;
typedef __attribute__((ext_vector_type(8))) short bf16x8;

__device__ __forceinline__ ushort f2bf(float f) {
    union { float f; unsigned u; } v; v.f = f;
    unsigned u = v.u;
    return (ushort)((u + 0x7fffu + ((u >> 16) & 1u)) >> 16);  // RNE
}

__device__ __forceinline__ void gload_lds16(const void* g, void* l) {
    __builtin_amdgcn_global_load_lds(
        (const __attribute__((address_space(1))) unsigned*)g,
        (__attribute__((address_space(3))) unsigned*)l, 16, 0, 0);
}

// ============================ primary path ============================

// Wt bf16, PRE-SWIZZLED: chunk j of row n (n = p*64+tag) stored at byte
// n*256 + (j^(n&7))*16.  Rows with tag>=50 are zero.  5120 threads.
__global__ void conv_k(const float* __restrict__ W, ushort* __restrict__ Wt) {
    int g = blockIdx.x * blockDim.x + threadIdx.x;   // flat chunk 0..5119
    if (g >= NZ * 16) return;
    int n = g >> 4, j = g & 15;
    int tg = n & 63, p = n >> 6;
    bf16x8 val = (bf16x8){0,0,0,0,0,0,0,0};
    if (tg < NTAGS) {
        const float* wp = W + tg * KD + p * EMB + j * 8;
        f32x4 lo = *(const f32x4*)wp;
        f32x4 hi = *(const f32x4*)(wp + 4);
        val[0]=(short)f2bf(lo[0]); val[1]=(short)f2bf(lo[1]);
        val[2]=(short)f2bf(lo[2]); val[3]=(short)f2bf(lo[3]);
        val[4]=(short)f2bf(hi[0]); val[5]=(short)f2bf(hi[1]);
        val[6]=(short)f2bf(hi[2]); val[7]=(short)f2bf(hi[3]);
    }
    *(bf16x8*)((char*)Wt + n * 256 + ((j ^ (n & 7)) << 4)) = val;
}

// ZT[v][p*64+tag] = emb[v] . W[tag][p*128 : p*128+128]   (bf16 out)
__global__ __launch_bounds__(256)
void zt_k(const float* __restrict__ emb, const ushort* __restrict__ Wt,
          ushort* __restrict__ ZT) {
    __shared__ __align__(16) char wlds[NZ * EMB * 2];   // 80 KB, chunk-swizzled

    const int tid  = threadIdx.x;
    const int lane = tid & 63;
    const int c = lane & 15, q = lane >> 4;
    const int vb = blockIdx.x * 128;
    const int wave = tid >> 6;

    // ---- issue E loads first (independent, fly under the W DMA) ----
    f32x4 Elo[2][4], Ehi[2][4];
    #pragma unroll
    for (int nv = 0; nv < 2; ++nv) {
        int row = vb + wave * 32 + nv * 16 + c;
        bool ok = row < VOCAB;
        const float* rp = emb + (size_t)(ok ? row : 0) * EMB;
        #pragma unroll
        for (int kk = 0; kk < 4; ++kk) {
            Elo[nv][kk] = ok ? *(const f32x4*)(rp + kk * 32 + q * 8)
                             : (f32x4){0,0,0,0};
            Ehi[nv][kk] = ok ? *(const f32x4*)(rp + kk * 32 + q * 8 + 4)
                             : (f32x4){0,0,0,0};
        }
    }

    // ---- stage W: 5120 chunks, linear async DMA (swizzle baked into Wt) ----
    #pragma unroll
    for (int it = 0; it < 20; ++it) {
        int g = it * 256 + tid;
        gload_lds16((const char*)Wt + g * 16, wlds + it * 4096 + wave * 1024);
    }

    // ---- convert E to bf16 (VALU; overlaps DMA drain) ----
    bf16x8 E[2][4];
    #pragma unroll
    for (int nv = 0; nv < 2; ++nv)
        #pragma unroll
        for (int kk = 0; kk < 4; ++kk) {
            bf16x8 a;
            a[0]=(short)f2bf(Elo[nv][kk][0]); a[1]=(short)f2bf(Elo[nv][kk][1]);
            a[2]=(short)f2bf(Elo[nv][kk][2]); a[3]=(short)f2bf(Elo[nv][kk][3]);
            a[4]=(short)f2bf(Ehi[nv][kk][0]); a[5]=(short)f2bf(Ehi[nv][kk][1]);
            a[6]=(short)f2bf(Ehi[nv][kk][2]); a[7]=(short)f2bf(Ehi[nv][kk][3]);
            E[nv][kk] = a;
        }
    __syncthreads();

    #pragma unroll
    for (int ng = 0; ng < 5; ++ng) {        // ng == position p
        bf16x8 Wf[4][4];
        #pragma unroll
        for (int mtag = 0; mtag < 4; ++mtag) {
            #pragma unroll
            for (int kk = 0; kk < 4; ++kk) {
                int r  = ng * 64 + mtag * 16 + c;         // Wt row
                int ph = (kk * 4 + q) ^ (c & 7);          // phys chunk (r&7 == c&7)
                Wf[mtag][kk] = *(const bf16x8*)(wlds + r * 256 + ph * 16);
            }
        }
        f32x4 acc[4][2];
        #pragma unroll
        for (int mtag = 0; mtag < 4; ++mtag)
            #pragma unroll
            for (int nv = 0; nv < 2; ++nv)
                acc[mtag][nv] = (f32x4){0.f,0.f,0.f,0.f};
        #pragma unroll
        for (int kk = 0; kk < 4; ++kk)
            #pragma unroll
            for (int mtag = 0; mtag < 4; ++mtag)
                #pragma unroll
                for (int nv = 0; nv < 2; ++nv)
                    acc[mtag][nv] = __builtin_amdgcn_mfma_f32_16x16x32_bf16(
                        Wf[mtag][kk], E[nv][kk], acc[mtag][nv], 0, 0, 0);
        #pragma unroll
        for (int nv = 0; nv < 2; ++nv) {
            const size_t row = (size_t)(vb + wave * 32 + nv * 16 + c);
            #pragma unroll
            for (int mtag = 0; mtag < 4; ++mtag) {
                ushort4 o = { f2bf(acc[mtag][nv][0]), f2bf(acc[mtag][nv][1]),
                              f2bf(acc[mtag][nv][2]), f2bf(acc[mtag][nv][3]) };
                *(ushort4*)(ZT + row * NZ + ng * 64 + mtag * 16 + q * 4) = o;
            }
        }
    }
}

// per 24-token block (R13 staging), TWO LANES PER TOKEN in the epilogue:
// lane = token*2 + half; each lane owns 32 tag slots (4 chunks/slice);
// pair-reduce softmax via shfl_xor(1); half-transpose + NT store pass.
__global__ __launch_bounds__(64, 1)
void tag_k(const int* __restrict__ tokens, const ushort* __restrict__ ZT,
           const float* __restrict__ bias, float* __restrict__ out) {
    __shared__ __align__(16) char smem[RWS * 640 + 128];   // rows + ids
    int* ids = (int*)(smem + RWS * 640);

    const int l  = threadIdx.x;
    const int bb = blockIdx.x * TOK;

    // ---- token ids for the 28 rows (row r <-> token bb-2+r) ----
    {
        int t = bb - 2 + l;
        if (l < RWS) ids[l] = ((unsigned)t < NTOK) ? tokens[t] : VOCAB; // zero row
    }
    __syncthreads();

    // ---- batched id reads into regs (mostly-broadcast LDS reads) ----
    int tk[NITER];
    #pragma unroll
    for (int w = 0; w < NITER; ++w) {
        int g = w * 64 + l;
        int r = (g < NCHUNK) ? (g / CHR) : 0;
        tk[w] = ids[r];
    }

    // ---- coalesced stage: flat chunk g = r*40 + p*8 + i  ->  LDS byte g*16.
    //      all DMA issues independent; source chunk pre-swizzled (i^(r&7)). ----
    #pragma unroll
    for (int w = 0; w < NITER; ++w) {
        int g = w * 64 + l;
        if (g < NCHUNK) {
            int r  = g / CHR;
            int ch = g - r * CHR;
            int i  = ch & 7, p = ch >> 3;
            const char* src = (const char*)ZT + (size_t)tk[w] * 640
                              + p * 128 + ((i ^ (r & 7)) << 4);
            gload_lds16(src, smem + w * 1024);
        }
    }
    __syncthreads();

    // ---- 2 lanes per token: lane = tkn*2 + h, lane owns tags h*32..h*32+31 ----
    const int tkn = ((l >> 1) < TOK) ? (l >> 1) : (TOK - 1);  // lanes 48+: dummy
    const int h   = l & 1;

    float acc[32];
    if (h == 0) {
        #pragma unroll
        for (int g = 0; g < 8; ++g) {
            float4 b4 = *(const float4*)(bias + g * 4);
            acc[g*4+0] = b4.x; acc[g*4+1] = b4.y; acc[g*4+2] = b4.z; acc[g*4+3] = b4.w;
        }
    } else {
        #pragma unroll
        for (int g = 0; g < 4; ++g) {
            float4 b4 = *(const float4*)(bias + 32 + g * 4);
            acc[g*4+0] = b4.x; acc[g*4+1] = b4.y; acc[g*4+2] = b4.z; acc[g*4+3] = b4.w;
        }
        acc[16] = bias[48]; acc[17] = bias[49];
        #pragma unroll
        for (int j = 18; j < 32; ++j) acc[j] = -1e30f;   // padded tag slots
    }

    // ---- window sum: slice p of token tkn is LDS row tkn+p, chunks 4h..4h+3 ----
    #pragma unroll
    for (int p = 0; p < 5; ++p) {
        const int rp = tkn + p;
        const char* rb = smem + rp * 640 + p * 128;
        const int rx = rp & 7;
        #pragma unroll
        for (int j = 0; j < 4; ++j) {
            bf16x8 v = *(const bf16x8*)(rb + (((4 * h + j) ^ rx) << 4));
            #pragma unroll
            for (int e = 0; e < 8; ++e) {
                unsigned u = (unsigned)(ushort)v[e] << 16;
                acc[j*8+e] += __uint_as_float(u);    // pads: -1e30 + 0
            }
        }
    }

    // ---- log-softmax: local 32 + pair reduce (shfl_xor 1) ----
    float m = acc[0];
    #pragma unroll
    for (int j = 1; j < 32; ++j) m = fmaxf(m, acc[j]);
    m = fmaxf(m, __shfl_xor(m, 1));
    float s = 0.f;
    #pragma unroll
    for (int j = 0; j < 32; ++j) s += __expf(acc[j] - m);   // pads -> 0
    s += __shfl_xor(s, 1);
    const float L = m + __logf(s);

    // ---- half-transpose into LDS, then NT full-line stores ----
    __syncthreads();
    if ((l >> 1) < TOK) {
        char* tb = smem + (size_t)tkn * 200 + h * 128;
        if (h == 0) {
            #pragma unroll
            for (int k = 0; k < 8; ++k) {
                f32x4 st = { acc[4*k]-L, acc[4*k+1]-L, acc[4*k+2]-L, acc[4*k+3]-L };
                *(f32x4*)(tb + k * 16) = st;
            }
        } else {
            #pragma unroll
            for (int k = 0; k < 4; ++k) {
                f32x4 st = { acc[4*k]-L, acc[4*k+1]-L, acc[4*k+2]-L, acc[4*k+3]-L };
                *(f32x4*)(tb + k * 16) = st;
            }
            float2 st2 = { acc[16] - L, acc[17] - L };      // tags 48,49
            *(float2*)(tb + 64) = st2;
        }
    }
    __syncthreads();
    const int nvalid = (NTOK - bb < TOK) ? (NTOK - bb) : TOK;
    const int nbytes = nvalid * 200;
    char* ob = (char*)out + (size_t)bb * 200;
    #pragma unroll
    for (int w = 0; w < 5; ++w) {
        int off = w * 1024 + l * 16;
        if (off < nbytes) {
            f32x4 d = *(const f32x4*)(smem + off);
            __builtin_nontemporal_store(d, (f32x4*)(ob + off));
        }
    }
}

// ============================ fallback path (R4, needs only ~13 MB ws) ============================
__global__ void fb_conv_k(const float* __restrict__ emb, const float* __restrict__ W,
                          ushort* __restrict__ embb, ushort* __restrict__ wb) {
    const int etotal = (VOCAB + 1) * EMB;
    int idx = (blockIdx.x * blockDim.x + threadIdx.x) * 4;
    if (idx < etotal) {
        float4 v = {0.f, 0.f, 0.f, 0.f};
        if (idx < VOCAB * EMB) v = *(const float4*)(emb + idx);
        ushort4 o = { f2bf(v.x), f2bf(v.y), f2bf(v.z), f2bf(v.w) };
        *(ushort4*)(embb + idx) = o;
    } else {
        int wi = idx - etotal;
        if (wi < WPAD * KD) {
            #pragma unroll
            for (int k = 0; k < 4; ++k) {
                int j = wi + k;
                int tag = j / KD;
                wb[j] = f2bf(tag < NTAGS ? W[j] : 0.f);
            }
        }
    }
}

__global__ __launch_bounds__(64, 2)
void fb_tag_k(const int* __restrict__ tokens, const ushort* __restrict__ embb,
              const ushort* __restrict__ Wb, const float* __restrict__ bias,
              float* __restrict__ out) {
    __shared__ ushort smem[68 * EMB];
    const int lane = threadIdx.x & 63;
    const int c = lane & 15;
    const int q = lane >> 4;
    const int bb = blockIdx.x * 64;
    const int rsub = lane >> 4;

    int tokid[17];
    #pragma unroll
    for (int g = 0; g < 17; ++g) {
        int t = bb - 2 + g * 4 + rsub;
        tokid[g] = (t >= 0 && t < NTOK) ? tokens[t] : VOCAB;
    }
    const ushort* bp[4];
    #pragma unroll
    for (int nt = 0; nt < 4; ++nt)
        bp[nt] = Wb + (nt * 16 + c) * KD + q * 8;
    bf16x8 Bb[4][4];
    #pragma unroll
    for (int s = 0; s < 4; ++s)
        #pragma unroll
        for (int nt = 0; nt < 4; ++nt)
            Bb[s][nt] = *(const bf16x8*)(bp[nt] + (s >> 2) * 128 + (s & 3) * 32);
    float bv[4];
    #pragma unroll
    for (int nt = 0; nt < 4; ++nt) {
        int tag = nt * 16 + c;
        bv[nt] = bias[tag < NTAGS ? tag : NTAGS - 1];
    }
    {
        const int pc = lane & 15;
        #pragma unroll
        for (int g = 0; g < 17; ++g) {
            int i = g * 4 + rsub;
            int sc = pc ^ (i & 7);
            gload_lds16(embb + (size_t)tokid[g] * EMB + sc * 8, (char*)smem + g * 1024);
        }
    }
    __syncthreads();

    f32x4 acc[4][4];
    #pragma unroll
    for (int mt = 0; mt < 4; ++mt)
        #pragma unroll
        for (int nt = 0; nt < 4; ++nt)
            acc[mt][nt] = (f32x4){0.f, 0.f, 0.f, 0.f};
    bf16x8 Ab[2][4];
    #pragma unroll
    for (int s = 0; s < 2; ++s) {
        int p = s >> 2, kk = s & 3;
        int ch = (4 * kk + q) ^ ((c + p) & 7);
        const char* ab = (const char*)smem + (c + p) * 256 + ch * 16;
        #pragma unroll
        for (int mt = 0; mt < 4; ++mt)
            Ab[s][mt] = *(const bf16x8*)(ab + mt * 4096);
    }
    #pragma unroll
    for (int s = 0; s < 20; ++s) {
        __builtin_amdgcn_s_setprio(1);
        #pragma unroll
        for (int mt = 0; mt < 4; ++mt)
            #pragma unroll
            for (int nt = 0; nt < 4; ++nt)
                acc[mt][nt] = __builtin_amdgcn_mfma_f32_16x16x32_bf16(
                    Ab[s & 1][mt], Bb[s & 3][nt], acc[mt][nt], 0, 0, 0);
        __builtin_amdgcn_s_setprio(0);
        if (s + 4 < 20) {
            const int tt = s + 4, p = tt >> 2, kk = tt & 3;
            #pragma unroll
            for (int nt = 0; nt < 4; ++nt)
                Bb[s & 3][nt] = *(const bf16x8*)(bp[nt] + p * 128 + kk * 32);
        }
        if (s + 2 < 20) {
            const int tt = s + 2, p = tt >> 2, kk = tt & 3;
            int ch = (4 * kk + q) ^ ((c + p) & 7);
            const char* ab = (const char*)smem + (c + p) * 256 + ch * 16;
            #pragma unroll
            for (int mt = 0; mt < 4; ++mt)
                Ab[s & 1][mt] = *(const bf16x8*)(ab + mt * 4096);
        }
    }
    #pragma unroll
    for (int mt = 0; mt < 4; ++mt) {
        #pragma unroll
        for (int j = 0; j < 4; ++j) {
            const int row = bb + mt * 16 + q * 4 + j;
            float x[4];
            float m = -1e30f;
            #pragma unroll
            for (int nt = 0; nt < 4; ++nt) {
                float xv = acc[mt][nt][j] + bv[nt];
                x[nt] = xv;
                if (nt * 16 + c < NTAGS) m = fmaxf(m, xv);
            }
            #pragma unroll
            for (int mask = 8; mask >= 1; mask >>= 1)
                m = fmaxf(m, __shfl_xor(m, mask));
            float s = 0.f;
            #pragma unroll
            for (int nt = 0; nt < 4; ++nt)
                if (nt * 16 + c < NTAGS) s += __expf(x[nt] - m);
            #pragma unroll
            for (int mask = 8; mask >= 1; mask >>= 1)
                s += __shfl_xor(s, mask);
            const float L = m + __logf(s);
            #pragma unroll
            for (int nt = 0; nt < 4; ++nt) {
                int tag = nt * 16 + c;
                if (tag < NTAGS) out[row * NTAGS + tag] = x[nt] - L;
            }
        }
    }
}

extern "C" void kernel_launch(void* const* d_in, const int* in_sizes, int n_in,
                              void* d_out, int out_size, void* d_ws, size_t ws_size,
                              hipStream_t stream) {
    const int*   tokens = (const int*)d_in[0];
    const float* emb    = (const float*)d_in[1];
    const float* W      = (const float*)d_in[2];
    const float* b      = (const float*)d_in[3];
    float* out = (float*)d_out;

    const size_t NEED = 81920ull + (size_t)ZROWS * NZ * 2ull;   // ~32.3 MB
    if (ws_size >= NEED) {
        ushort* Wt = (ushort*)d_ws;                             // 80 KB pre-swizzled
        ushort* ZT = (ushort*)((char*)d_ws + 81920);            // ZROWS x 320 bf16
        conv_k<<<20, 256, 0, stream>>>(W, Wt);
        zt_k<<<ZROWS / 128, 256, 0, stream>>>(emb, Wt, ZT);
        tag_k<<<(NTOK + TOK - 1) / TOK, 64, 0, stream>>>(tokens, ZT, b, out);
    } else {
        ushort* embb = (ushort*)d_ws;
        ushort* Wb   = embb + (size_t)(VOCAB + 1) * EMB;
        const int etotal = (VOCAB + 1) * EMB;
        const int total4 = (etotal + WPAD * KD) / 4;
        fb_conv_k<<<(total4 + 255) / 256, 256, 0, stream>>>(emb, W, embb, Wb);
        fb_tag_k<<<NTOK / 64, 64, 0, stream>>>(tokens, embb, Wb, b, out);
    }
}

// Round 18
// 65.634 us; speedup vs baseline: 1.1601x; 1.0150x over previous
//
#include <hip/hip_runtime.h>
#include <hip/hip_bf16.h>

#define VOCAB 50257
#define NTAGS 50
#define EMB   128
#define NTOK  262144
#define KD    640     // (2*CTX+1) * EMB
#define WPAD  64      // (fallback) tags padded to 4 MFMA tiles

#define TAGP  64      // per-position padded tag slots in ZT (slice = 128 B)
#define NZ    320     // 5 positions * TAGP
#define ZROWS 50304   // 393*128 rows (rows >= VOCAB are zero sentinels)

#define TOK   24      // tokens per tag_k block
#define RWS   28      // staged rows (24 + 4 halo)
#define CHR   35      // 16B chunks staged per row: 5 slices x 7 (tags 0-55 only)
#define NCHUNK (RWS*CHR)          // 980
#define NITER  ((NCHUNK+63)/64)   // 16
#define ROWB   560                // staged row bytes (35*16)

typedef __attribute__((ext_vector_type(4))) float f32x4;
typedef __attribute__((ext_vector_type(8))) short bf16x8;

__device__ __forceinline__ ushort f2bf(float f) {
    union { float f; unsigned u; } v; v.f = f;
    unsigned u = v.u;
    return (ushort)((u + 0x7fffu + ((u >> 16) & 1u)) >> 16);  // RNE
}

__device__ __forceinline__ void gload_lds16(const void* g, void* l) {
    __builtin_amdgcn_global_load_lds(
        (const __attribute__((address_space(1))) unsigned*)g,
        (__attribute__((address_space(3))) unsigned*)l, 16, 0, 0);
}

// ============================ primary path ============================

// Wt bf16, PRE-SWIZZLED for zt_k's LDS: chunk j of row n (n = p*64+tag) at
// byte n*256 + (j^(n&7))*16.  Rows with tag>=50 are zero.  5120 threads.
__global__ void conv_k(const float* __restrict__ W, ushort* __restrict__ Wt) {
    int g = blockIdx.x * blockDim.x + threadIdx.x;   // flat chunk 0..5119
    if (g >= NZ * 16) return;
    int n = g >> 4, j = g & 15;
    int tg = n & 63, p = n >> 6;
    bf16x8 val = (bf16x8){0,0,0,0,0,0,0,0};
    if (tg < NTAGS) {
        const float* wp = W + tg * KD + p * EMB + j * 8;
        f32x4 lo = *(const f32x4*)wp;
        f32x4 hi = *(const f32x4*)(wp + 4);
        val[0]=(short)f2bf(lo[0]); val[1]=(short)f2bf(lo[1]);
        val[2]=(short)f2bf(lo[2]); val[3]=(short)f2bf(lo[3]);
        val[4]=(short)f2bf(hi[0]); val[5]=(short)f2bf(hi[1]);
        val[6]=(short)f2bf(hi[2]); val[7]=(short)f2bf(hi[3]);
    }
    *(bf16x8*)((char*)Wt + n * 256 + ((j ^ (n & 7)) << 4)) = val;
}

// ZT[v][p*64+tag] = emb[v] . W[tag][p*128 : p*128+128]   (bf16 out)
// tags 56-63 never read downstream -> their stores skipped.
__global__ __launch_bounds__(256)
void zt_k(const float* __restrict__ emb, const ushort* __restrict__ Wt,
          ushort* __restrict__ ZT) {
    __shared__ __align__(16) char wlds[NZ * EMB * 2];   // 80 KB, chunk-swizzled

    const int tid  = threadIdx.x;
    const int lane = tid & 63;
    const int c = lane & 15, q = lane >> 4;
    const int vb = blockIdx.x * 128;
    const int wave = tid >> 6;

    // ---- issue E loads first (independent, fly under the W DMA) ----
    f32x4 Elo[2][4], Ehi[2][4];
    #pragma unroll
    for (int nv = 0; nv < 2; ++nv) {
        int row = vb + wave * 32 + nv * 16 + c;
        bool ok = row < VOCAB;
        const float* rp = emb + (size_t)(ok ? row : 0) * EMB;
        #pragma unroll
        for (int kk = 0; kk < 4; ++kk) {
            Elo[nv][kk] = ok ? *(const f32x4*)(rp + kk * 32 + q * 8)
                             : (f32x4){0,0,0,0};
            Ehi[nv][kk] = ok ? *(const f32x4*)(rp + kk * 32 + q * 8 + 4)
                             : (f32x4){0,0,0,0};
        }
    }

    // ---- stage W: 5120 chunks, linear async DMA (swizzle baked into Wt) ----
    #pragma unroll
    for (int it = 0; it < 20; ++it) {
        int g = it * 256 + tid;
        gload_lds16((const char*)Wt + g * 16, wlds + it * 4096 + wave * 1024);
    }

    // ---- convert E to bf16 (VALU; overlaps DMA drain) ----
    bf16x8 E[2][4];
    #pragma unroll
    for (int nv = 0; nv < 2; ++nv)
        #pragma unroll
        for (int kk = 0; kk < 4; ++kk) {
            bf16x8 a;
            a[0]=(short)f2bf(Elo[nv][kk][0]); a[1]=(short)f2bf(Elo[nv][kk][1]);
            a[2]=(short)f2bf(Elo[nv][kk][2]); a[3]=(short)f2bf(Elo[nv][kk][3]);
            a[4]=(short)f2bf(Ehi[nv][kk][0]); a[5]=(short)f2bf(Ehi[nv][kk][1]);
            a[6]=(short)f2bf(Ehi[nv][kk][2]); a[7]=(short)f2bf(Ehi[nv][kk][3]);
            E[nv][kk] = a;
        }
    __syncthreads();

    #pragma unroll
    for (int ng = 0; ng < 5; ++ng) {        // ng == position p
        bf16x8 Wf[4][4];
        #pragma unroll
        for (int mtag = 0; mtag < 4; ++mtag) {
            #pragma unroll
            for (int kk = 0; kk < 4; ++kk) {
                int r  = ng * 64 + mtag * 16 + c;         // Wt row
                int ph = (kk * 4 + q) ^ (c & 7);          // phys chunk (r&7 == c&7)
                Wf[mtag][kk] = *(const bf16x8*)(wlds + r * 256 + ph * 16);
            }
        }
        f32x4 acc[4][2];
        #pragma unroll
        for (int mtag = 0; mtag < 4; ++mtag)
            #pragma unroll
            for (int nv = 0; nv < 2; ++nv)
                acc[mtag][nv] = (f32x4){0.f,0.f,0.f,0.f};
        #pragma unroll
        for (int kk = 0; kk < 4; ++kk)
            #pragma unroll
            for (int mtag = 0; mtag < 4; ++mtag)
                #pragma unroll
                for (int nv = 0; nv < 2; ++nv)
                    acc[mtag][nv] = __builtin_amdgcn_mfma_f32_16x16x32_bf16(
                        Wf[mtag][kk], E[nv][kk], acc[mtag][nv], 0, 0, 0);
        #pragma unroll
        for (int nv = 0; nv < 2; ++nv) {
            const size_t row = (size_t)(vb + wave * 32 + nv * 16 + c);
            #pragma unroll
            for (int mtag = 0; mtag < 4; ++mtag) {
                if (mtag < 3 || q < 2) {   // tags 56-63 never read: skip
                    ushort4 o = { f2bf(acc[mtag][nv][0]), f2bf(acc[mtag][nv][1]),
                                  f2bf(acc[mtag][nv][2]), f2bf(acc[mtag][nv][3]) };
                    *(ushort4*)(ZT + row * NZ + ng * 64 + mtag * 16 + q * 4) = o;
                }
            }
        }
    }
}

// per 24-token block: ids->LDS prefetch, 16 independent DMAs staging a PACKED
// 7-chunk/slice tile (tags 0-55 only, 560B rows, no swizzle); 2 lanes/token
// window-sum; pair softmax; NT stores.  h=1's 4th chunk read is redirected to
// the slice's chunk 0 (always-staged FINITE ZT data) — never reinterpreted
// int bytes, so the -1e30 pad accumulators cannot be poisoned by inf/NaN.
__global__ __launch_bounds__(64, 1)
void tag_k(const int* __restrict__ tokens, const ushort* __restrict__ ZT,
           const float* __restrict__ bias, float* __restrict__ out) {
    __shared__ __align__(16) char smem[RWS * ROWB + 128];   // rows + ids
    int* ids = (int*)(smem + RWS * ROWB);

    const int l  = threadIdx.x;
    const int bb = blockIdx.x * TOK;

    // ---- token ids for the 28 rows (row r <-> token bb-2+r) ----
    {
        int t = bb - 2 + l;
        if (l < RWS) ids[l] = ((unsigned)t < NTOK) ? tokens[t] : VOCAB; // zero row
    }
    __syncthreads();

    // ---- batched id reads into regs ----
    int tk[NITER];
    #pragma unroll
    for (int w = 0; w < NITER; ++w) {
        int g = w * 64 + l;
        int r = (g < NCHUNK) ? (g / CHR) : 0;
        tk[w] = ids[r];
    }

    // ---- packed stage: flat chunk g = r*35 + p*7 + i  ->  LDS byte g*16.
    //      source byte = row*640 + p*128 + i*16 (skips chunk 7 = tags 56-63) ----
    #pragma unroll
    for (int w = 0; w < NITER; ++w) {
        int g = w * 64 + l;
        if (g < NCHUNK) {
            int r  = g / CHR;
            int ch = g - r * CHR;
            int p  = ch / 7, i = ch - p * 7;
            const char* src = (const char*)ZT + (size_t)tk[w] * 640
                              + p * 128 + (i << 4);
            gload_lds16(src, smem + w * 1024);
        }
    }
    __syncthreads();

    // ---- 2 lanes/token: lane = tkn*2+h owns bytes h*64.. of each 112B slice.
    //      h=1's j=3 chunk is a SAFE duplicate read (slice chunk 0) absorbed
    //      by -1e30 pads. ----
    const int tkn = ((l >> 1) < TOK) ? (l >> 1) : (TOK - 1);  // lanes 48+: dummy
    const int h   = l & 1;

    float acc[32];
    if (h == 0) {
        #pragma unroll
        for (int g = 0; g < 8; ++g) {
            float4 b4 = *(const float4*)(bias + g * 4);
            acc[g*4+0] = b4.x; acc[g*4+1] = b4.y; acc[g*4+2] = b4.z; acc[g*4+3] = b4.w;
        }
    } else {
        #pragma unroll
        for (int g = 0; g < 4; ++g) {
            float4 b4 = *(const float4*)(bias + 32 + g * 4);
            acc[g*4+0] = b4.x; acc[g*4+1] = b4.y; acc[g*4+2] = b4.z; acc[g*4+3] = b4.w;
        }
        acc[16] = bias[48]; acc[17] = bias[49];
        #pragma unroll
        for (int j = 18; j < 32; ++j) acc[j] = -1e30f;  // ZT pads + dup chunk
    }

    const int off3 = h ? -64 : 48;   // j=3 chunk: h=0 -> valid chunk 3;
                                     // h=1 -> slice chunk 0 (finite dup)
    #pragma unroll
    for (int p = 0; p < 5; ++p) {
        const char* rb = smem + (tkn + p) * ROWB + p * 112 + h * 64;
        #pragma unroll
        for (int j = 0; j < 4; ++j) {
            const char* ap = (j == 3) ? (rb + off3) : (rb + j * 16);
            bf16x8 v = *(const bf16x8*)ap;
            #pragma unroll
            for (int e = 0; e < 8; ++e) {
                unsigned u = (unsigned)(ushort)v[e] << 16;
                acc[j*8+e] += __uint_as_float(u);
            }
        }
    }

    // ---- log-softmax: local 32 + pair reduce (shfl_xor 1) ----
    float m = acc[0];
    #pragma unroll
    for (int j = 1; j < 32; ++j) m = fmaxf(m, acc[j]);
    m = fmaxf(m, __shfl_xor(m, 1));
    float s = 0.f;
    #pragma unroll
    for (int j = 0; j < 32; ++j) s += __expf(acc[j] - m);   // pads -> 0
    s += __shfl_xor(s, 1);
    const float L = m + __logf(s);

    // ---- half-transpose into LDS, then NT full-line stores ----
    __syncthreads();
    if ((l >> 1) < TOK) {
        char* tb = smem + (size_t)tkn * 200 + h * 128;
        if (h == 0) {
            #pragma unroll
            for (int k = 0; k < 8; ++k) {
                f32x4 st = { acc[4*k]-L, acc[4*k+1]-L, acc[4*k+2]-L, acc[4*k+3]-L };
                *(f32x4*)(tb + k * 16) = st;
            }
        } else {
            #pragma unroll
            for (int k = 0; k < 4; ++k) {
                f32x4 st = { acc[4*k]-L, acc[4*k+1]-L, acc[4*k+2]-L, acc[4*k+3]-L };
                *(f32x4*)(tb + k * 16) = st;
            }
            float2 st2 = { acc[16] - L, acc[17] - L };      // tags 48,49
            *(float2*)(tb + 64) = st2;
        }
    }
    __syncthreads();
    const int nvalid = (NTOK - bb < TOK) ? (NTOK - bb) : TOK;
    const int nbytes = nvalid * 200;
    char* ob = (char*)out + (size_t)bb * 200;
    #pragma unroll
    for (int w = 0; w < 5; ++w) {
        int off = w * 1024 + l * 16;
        if (off < nbytes) {
            f32x4 d = *(const f32x4*)(smem + off);
            __builtin_nontemporal_store(d, (f32x4*)(ob + off));
        }
    }
}

// ============================ fallback path (R4, needs only ~13 MB ws) ============================
__global__ void fb_conv_k(const float* __restrict__ emb, const float* __restrict__ W,
                          ushort* __restrict__ embb, ushort* __restrict__ wb) {
    const int etotal = (VOCAB + 1) * EMB;
    int idx = (blockIdx.x * blockDim.x + threadIdx.x) * 4;
    if (idx < etotal) {
        float4 v = {0.f, 0.f, 0.f, 0.f};
        if (idx < VOCAB * EMB) v = *(const float4*)(emb + idx);
        ushort4 o = { f2bf(v.x), f2bf(v.y), f2bf(v.z), f2bf(v.w) };
        *(ushort4*)(embb + idx) = o;
    } else {
        int wi = idx - etotal;
        if (wi < WPAD * KD) {
            #pragma unroll
            for (int k = 0; k < 4; ++k) {
                int j = wi + k;
                int tag = j / KD;
                wb[j] = f2bf(tag < NTAGS ? W[j] : 0.f);
            }
        }
    }
}

__global__ __launch_bounds__(64, 2)
void fb_tag_k(const int* __restrict__ tokens, const ushort* __restrict__ embb,
              const ushort* __restrict__ Wb, const float* __restrict__ bias,
              float* __restrict__ out) {
    __shared__ ushort smem[68 * EMB];
    const int lane = threadIdx.x & 63;
    const int c = lane & 15;
    const int q = lane >> 4;
    const int bb = blockIdx.x * 64;
    const int rsub = lane >> 4;

    int tokid[17];
    #pragma unroll
    for (int g = 0; g < 17; ++g) {
        int t = bb - 2 + g * 4 + rsub;
        tokid[g] = (t >= 0 && t < NTOK) ? tokens[t] : VOCAB;
    }
    const ushort* bp[4];
    #pragma unroll
    for (int nt = 0; nt < 4; ++nt)
        bp[nt] = Wb + (nt * 16 + c) * KD + q * 8;
    bf16x8 Bb[4][4];
    #pragma unroll
    for (int s = 0; s < 4; ++s)
        #pragma unroll
        for (int nt = 0; nt < 4; ++nt)
            Bb[s][nt] = *(const bf16x8*)(bp[nt] + (s >> 2) * 128 + (s & 3) * 32);
    float bv[4];
    #pragma unroll
    for (int nt = 0; nt < 4; ++nt) {
        int tag = nt * 16 + c;
        bv[nt] = bias[tag < NTAGS ? tag : NTAGS - 1];
    }
    {
        const int pc = lane & 15;
        #pragma unroll
        for (int g = 0; g < 17; ++g) {
            int i = g * 4 + rsub;
            int sc = pc ^ (i & 7);
            gload_lds16(embb + (size_t)tokid[g] * EMB + sc * 8, (char*)smem + g * 1024);
        }
    }
    __syncthreads();

    f32x4 acc[4][4];
    #pragma unroll
    for (int mt = 0; mt < 4; ++mt)
        #pragma unroll
        for (int nt = 0; nt < 4; ++nt)
            acc[mt][nt] = (f32x4){0.f, 0.f, 0.f, 0.f};
    bf16x8 Ab[2][4];
    #pragma unroll
    for (int s = 0; s < 2; ++s) {
        int p = s >> 2, kk = s & 3;
        int ch = (4 * kk + q) ^ ((c + p) & 7);
        const char* ab = (const char*)smem + (c + p) * 256 + ch * 16;
        #pragma unroll
        for (int mt = 0; mt < 4; ++mt)
            Ab[s][mt] = *(const bf16x8*)(ab + mt * 4096);
    }
    #pragma unroll
    for (int s = 0; s < 20; ++s) {
        __builtin_amdgcn_s_setprio(1);
        #pragma unroll
        for (int mt = 0; mt < 4; ++mt)
            #pragma unroll
            for (int nt = 0; nt < 4; ++nt)
                acc[mt][nt] = __builtin_amdgcn_mfma_f32_16x16x32_bf16(
                    Ab[s & 1][mt], Bb[s & 3][nt], acc[mt][nt], 0, 0, 0);
        __builtin_amdgcn_s_setprio(0);
        if (s + 4 < 20) {
            const int tt = s + 4, p = tt >> 2, kk = tt & 3;
            #pragma unroll
            for (int nt = 0; nt < 4; ++nt)
                Bb[s & 3][nt] = *(const bf16x8*)(bp[nt] + p * 128 + kk * 32);
        }
        if (s + 2 < 20) {
            const int tt = s + 2, p = tt >> 2, kk = tt & 3;
            int ch = (4 * kk + q) ^ ((c + p) & 7);
            const char* ab = (const char*)smem + (c + p) * 256 + ch * 16;
            #pragma unroll
            for (int mt = 0; mt < 4; ++mt)
                Ab[s & 1][mt] = *(const bf16x8*)(ab + mt * 4096);
        }
    }
    #pragma unroll
    for (int mt = 0; mt < 4; ++mt) {
        #pragma unroll
        for (int j = 0; j < 4; ++j) {
            const int row = bb + mt * 16 + q * 4 + j;
            float x[4];
            float m = -1e30f;
            #pragma unroll
            for (int nt = 0; nt < 4; ++nt) {
                float xv = acc[mt][nt][j] + bv[nt];
                x[nt] = xv;
                if (nt * 16 + c < NTAGS) m = fmaxf(m, xv);
            }
            #pragma unroll
            for (int mask = 8; mask >= 1; mask >>= 1)
                m = fmaxf(m, __shfl_xor(m, mask));
            float s = 0.f;
            #pragma unroll
            for (int nt = 0; nt < 4; ++nt)
                if (nt * 16 + c < NTAGS) s += __expf(x[nt] - m);
            #pragma unroll
            for (int mask = 8; mask >= 1; mask >>= 1)
                s += __shfl_xor(s, mask);
            const float L = m + __logf(s);
            #pragma unroll
            for (int nt = 0; nt < 4; ++nt) {
                int tag = nt * 16 + c;
                if (tag < NTAGS) out[row * NTAGS + tag] = x[nt] - L;
            }
        }
    }
}

extern "C" void kernel_launch(void* const* d_in, const int* in_sizes, int n_in,
                              void* d_out, int out_size, void* d_ws, size_t ws_size,
                              hipStream_t stream) {
    const int*   tokens = (const int*)d_in[0];
    const float* emb    = (const float*)d_in[1];
    const float* W      = (const float*)d_in[2];
    const float* b      = (const float*)d_in[3];
    float* out = (float*)d_out;

    const size_t NEED = 81920ull + (size_t)ZROWS * NZ * 2ull;   // ~32.3 MB
    if (ws_size >= NEED) {
        ushort* Wt = (ushort*)d_ws;                             // 80 KB pre-swizzled
        ushort* ZT = (ushort*)((char*)d_ws + 81920);            // ZROWS x 320 bf16
        conv_k<<<20, 256, 0, stream>>>(W, Wt);
        zt_k<<<ZROWS / 128, 256, 0, stream>>>(emb, Wt, ZT);
        tag_k<<<(NTOK + TOK - 1) / TOK, 64, 0, stream>>>(tokens, ZT, b, out);
    } else {
        ushort* embb = (ushort*)d_ws;
        ushort* Wb   = embb + (size_t)(VOCAB + 1) * EMB;
        const int etotal = (VOCAB + 1) * EMB;
        const int total4 = (etotal + WPAD * KD) / 4;
        fb_conv_k<<<(total4 + 255) / 256, 256, 0, stream>>>(emb, W, embb, Wb);
        fb_tag_k<<<NTOK / 64, 64, 0, stream>>>(tokens, embb, Wb, b, out);
    }
}